// Round 7
// baseline (329.622 us; speedup 1.0000x reference)
//
#include <hip/hip_runtime.h>
#include <stdint.h>

#define B_   4
#define C_   256
#define HW_  16384
#define P_   2048
#define THR_ 0.8f
#define INV_ 0.9999950000374997f

// ncand padded: counter b lives at ncand[b*16] (64 B apart -> no cacheline sharing)
#define NCIDX(b) ((b) << 4)

// ---------------- workspace layout (bytes) ----------------
#define OFF_NCAND 0
#define OFF_CAND  256                       // u64 cand[4][HW_]   512 KB
#define OFF_TOPK  524544                    // int topk[4][P_]     32 KB
#define OFF_POS   557312                    // int pos[4][HW_]    256 KB
#define OFF_G     819456                    // f32 r[4][C_][P_]     8 MB (GEMM2 out)
#define OFF_GT    9208064                   // bf16 gT[4][C_][P_]   4 MB  == [1024][2048]
#define OFF_Z2    13402368                  // bf16 z2[4][P_][C_]   4 MB  == [8192][256]
#define OFF_WADJB 17596672                  // bf16 Wadj[2048][2048] 8 MB
#define OFF_WGB   25985280                  // bf16 Wg[256][256]  128 KB
#define OFF_R     OFF_G
#define OFF_RANK  OFF_Z2                    // int rank[4][HW_] 256 KB, aliases z2 (dead before gemm1)

typedef __attribute__((ext_vector_type(8))) short bf16x8;
typedef __attribute__((ext_vector_type(4))) float f32x4;

__device__ __forceinline__ ushort f2bf(float f) {
    union { float f; unsigned u; } a; a.f = f;
    unsigned r = (a.u + 0x7fffu + ((a.u >> 16) & 1u)) >> 16;   // RNE
    return (ushort)r;
}
__device__ __forceinline__ float bf2f(ushort u) {
    union { unsigned u; float f; } a; a.u = (unsigned)u << 16;
    return a.f;
}

// Fused prep: convert Wadj (4096 blocks) + convert Wg (64 blocks) + zero pos/rank/ncand (128 blocks)
#define PREP_WADJ_BLOCKS 4096               // P_*P_/4/256
#define PREP_WG_BLOCKS   64                 // C_*C_/4/256
#define PREP_ZERO_BLOCKS 128                // (B_*HW_/4)*2 / 256
#define PREP_GRID (PREP_WADJ_BLOCKS + PREP_WG_BLOCKS + PREP_ZERO_BLOCKS)

__global__ __launch_bounds__(256) void prep_kernel(const float* __restrict__ Wadj,
                                                   ushort* __restrict__ WadjB,
                                                   const float* __restrict__ Wg,
                                                   ushort* __restrict__ WgB,
                                                   int* __restrict__ pos,
                                                   int* __restrict__ rankbuf,
                                                   int* __restrict__ ncand) {
    int bid = blockIdx.x;
    if (bid < PREP_WADJ_BLOCKS) {
        int i = bid * 256 + threadIdx.x;
        float4 v = ((const float4*)Wadj)[i];
        ushort4 o; o.x = f2bf(v.x); o.y = f2bf(v.y); o.z = f2bf(v.z); o.w = f2bf(v.w);
        ((ushort4*)WadjB)[i] = o;
    } else if (bid < PREP_WADJ_BLOCKS + PREP_WG_BLOCKS) {
        int i = (bid - PREP_WADJ_BLOCKS) * 256 + threadIdx.x;
        float4 v = ((const float4*)Wg)[i];
        ushort4 o; o.x = f2bf(v.x); o.y = f2bf(v.y); o.z = f2bf(v.z); o.w = f2bf(v.w);
        ((ushort4*)WgB)[i] = o;
    } else {
        int zb = bid - PREP_WADJ_BLOCKS - PREP_WG_BLOCKS;
        int i = zb * 256 + threadIdx.x;                // 0 .. 32767 (int4 units)
        int4 z = {0, 0, 0, 0};
        if (i < B_ * HW_ / 4) ((int4*)pos)[i] = z;
        else                  ((int4*)rankbuf)[i - B_ * HW_ / 4] = z;
        if (zb == 0 && threadIdx.x < 64) ncand[threadIdx.x] = 0;   // covers all padded slots
    }
}

// Block-aggregated compact: ballot+popcount per wave, LDS prefix across 4 waves,
// ONE global atomicAdd per block (256 total, padded counters). R6: -11.5us vs
// per-lane atomics on one shared cacheline.
__global__ __launch_bounds__(256) void compact_kernel(const float* __restrict__ edge,
                                                      unsigned long long* __restrict__ cand,
                                                      int* __restrict__ ncand) {
    int b = blockIdx.x >> 6;
    int i = (blockIdx.x & 63) * 256 + threadIdx.x;
    float e = edge[b * HW_ + i];
    bool act = (e >= THR_);
    unsigned long long mask = __ballot(act);
    int lane = threadIdx.x & 63;
    int wid  = threadIdx.x >> 6;
    int before = __popcll(mask & ((1ull << lane) - 1ull));
    __shared__ int wcnt[4];
    __shared__ int base;
    if (lane == 0) wcnt[wid] = __popcll(mask);
    __syncthreads();
    if (threadIdx.x == 0) {
        int c0 = wcnt[0], c1 = wcnt[1], c2 = wcnt[2], c3 = wcnt[3];
        wcnt[0] = 0; wcnt[1] = c0; wcnt[2] = c0 + c1; wcnt[3] = c0 + c1 + c2;
        base = atomicAdd(&ncand[NCIDX(b)], c0 + c1 + c2 + c3);
    }
    __syncthreads();
    if (act) {
        int slot = base + wcnt[wid] + before;
        unsigned vb = __float_as_uint(e);
        cand[(size_t)b * HW_ + slot] =
            ((unsigned long long)vb << 32) | (unsigned long long)(0xFFFFFFFFu - (unsigned)i);
    }
}

// 2-D partial rank: block (jb, tb, b) counts, for each candidate j in jb-tile,
// how many candidates in tb-tile compare greater. atomicAdd into rankbuf[j].
// NOTE R4 lesson: 2x2 super-tiling regressed ~+18us — empty-block dispatch is
// nearly free; work concentration isn't.
__global__ __launch_bounds__(256) void rank_partial_kernel(
        const unsigned long long* __restrict__ cand,
        const int* __restrict__ ncand,
        int* __restrict__ rankbuf) {
    int b = blockIdx.z;
    int n = ncand[NCIDX(b)];
    int jb = blockIdx.x * 256, tb = blockIdx.y * 256;
    if (jb >= n || tb >= n) return;
    const unsigned long long* cb = cand + (size_t)b * HW_;
    __shared__ unsigned long long tile[256];
    int j = jb + threadIdx.x;
    unsigned long long kj = (j < n) ? cb[j] : 0ull;
    tile[threadIdx.x] = (tb + (int)threadIdx.x < n) ? cb[tb + threadIdx.x] : 0ull;
    __syncthreads();
    int cnt = 0;
#pragma unroll 16
    for (int k = 0; k < 256; ++k) cnt += (tile[k] > kj) ? 1 : 0;   // padded zeros never count
    if (j < n && cnt) atomicAdd(&rankbuf[b * HW_ + j], cnt);
}

// rank < P -> topk[rank]=idx, pos[idx]=rank+1.  Fallback (n < P) folded in.
__global__ __launch_bounds__(256) void rank_finalize_kernel(
        const unsigned long long* __restrict__ cand,
        const int* __restrict__ ncand,
        const int* __restrict__ rankbuf,
        int* __restrict__ topk,
        int* __restrict__ pos,
        const float* __restrict__ edge) {
    int b = blockIdx.y;
    int n = ncand[NCIDX(b)];
    int j = blockIdx.x * 256 + threadIdx.x;
    if (j < n) {
        int rank = rankbuf[b * HW_ + j];
        if (rank < P_) {
            int idx = (int)(0xFFFFFFFFu - (unsigned)(cand[(size_t)b * HW_ + j] & 0xFFFFFFFFull));
            topk[b * P_ + rank] = idx;
            pos[b * HW_ + idx] = rank + 1;
        }
    }
    if (n < P_ && blockIdx.x == 0 && threadIdx.x == 0) {
        int cnt = n;
        for (int i = 0; i < HW_ && cnt < P_; ++i) {
            if (edge[b * HW_ + i] < THR_) {
                topk[b * P_ + cnt] = i;
                pos[b * HW_ + i] = cnt + 1;
                cnt++;
            }
        }
    }
}

// index-driven gather: one block per (b,c) row; stage x-row in LDS (coalesced),
// gather topk positions from LDS, write gT row fully coalesced (16B/thread runs).
__global__ __launch_bounds__(256) void gather_lds_kernel(const float* __restrict__ x,
                                                         const int* __restrict__ topk,
                                                         ushort* __restrict__ gT) {
    __shared__ float row[HW_];              // 64 KB -> 2 blocks/CU
    int bc = blockIdx.x;                    // b*C_ + c
    int b = bc >> 8;
    const float* xr = x + (size_t)bc * HW_;
#pragma unroll
    for (int i = 0; i < 16; ++i)
        ((float4*)row)[threadIdx.x + i * 256] = ((const float4*)xr)[threadIdx.x + i * 256];
    __syncthreads();
    const int* tk = topk + b * P_;
    int p0 = threadIdx.x * 8;
    int4 i0 = *(const int4*)&tk[p0];
    int4 i1 = *(const int4*)&tk[p0 + 4];
    ushort4 o0, o1;
    o0.x = f2bf(row[i0.x]); o0.y = f2bf(row[i0.y]); o0.z = f2bf(row[i0.z]); o0.w = f2bf(row[i0.w]);
    o1.x = f2bf(row[i1.x]); o1.y = f2bf(row[i1.y]); o1.z = f2bf(row[i1.z]); o1.w = f2bf(row[i1.w]);
    ushort* gp = gT + (size_t)bc * P_ + p0;
    *(ushort4*)gp = o0;
    *(ushort4*)(gp + 4) = o1;
}

// ------------------- per-wave NT MFMA GEMM, no LDS, no barriers -------------------
#define MFMA16(AB, BB)                                                              \
    _Pragma("unroll")                                                               \
    for (int i = 0; i < 4; ++i)                                                     \
    _Pragma("unroll")                                                               \
        for (int j = 0; j < 4; ++j)                                                 \
            acc[i][j] = __builtin_amdgcn_mfma_f32_16x16x32_bf16(                    \
                __builtin_bit_cast(bf16x8, AB[i]),                                  \
                __builtin_bit_cast(bf16x8, BB[j]), acc[i][j], 0, 0, 0);

// MODE 1 (gemm1): M=2048 (o), N=1024 (b*256+c), K=2048
// MODE 2 (gemm2): M=256 (d), N=8192 (b*2048+p), K=256
template<int MODE, int KDIM, int NTN, int WPB>
__global__ __launch_bounds__(64 * WPB) void gemm_wave_kernel(
        const ushort* __restrict__ A, const ushort* __restrict__ B,
        const float* __restrict__ gamma, const float* __restrict__ beta,
        const ushort* __restrict__ residT, void* __restrict__ out) {
    constexpr int KSTEPS = KDIM / 32;
    const int bid = blockIdx.x;
    const int wid = threadIdx.x >> 6;        // wave within block (0..WPB-1)
    const int mt = (bid / NTN) * WPB + wid;
    const int nt = bid % NTN;
    const int lane = threadIdx.x & 63;       // 0..63
    const int quad = lane >> 4, ln = lane & 15;

    const ushort* pa[4];
    const ushort* pb[4];
#pragma unroll
    for (int i = 0; i < 4; ++i) {
        pa[i] = A + (size_t)(mt * 64 + i * 16 + ln) * KDIM + quad * 8;
        pb[i] = B + (size_t)(nt * 64 + i * 16 + ln) * KDIM + quad * 8;
    }

    f32x4 acc[4][4];
#pragma unroll
    for (int i = 0; i < 4; ++i)
#pragma unroll
        for (int j = 0; j < 4; ++j) acc[i][j] = (f32x4){0.f, 0.f, 0.f, 0.f};

    uint4 a0[4], b0[4], a1[4], b1[4];
#pragma unroll
    for (int i = 0; i < 4; ++i) {
        a0[i] = *(const uint4*)(pa[i]);
        b0[i] = *(const uint4*)(pb[i]);
        a1[i] = *(const uint4*)(pa[i] + 32);
        b1[i] = *(const uint4*)(pb[i] + 32);
    }

    int koff = 64;
    for (int s = 0; s < KSTEPS - 2; s += 2) {
        MFMA16(a0, b0)
#pragma unroll
        for (int i = 0; i < 4; ++i) {
            a0[i] = *(const uint4*)(pa[i] + koff);
            b0[i] = *(const uint4*)(pb[i] + koff);
        }
        MFMA16(a1, b1)
#pragma unroll
        for (int i = 0; i < 4; ++i) {
            a1[i] = *(const uint4*)(pa[i] + koff + 32);
            b1[i] = *(const uint4*)(pb[i] + koff + 32);
        }
        koff += 64;
    }
    MFMA16(a0, b0)
    MFMA16(a1, b1)

    float gm[16], bt[16];
#pragma unroll
    for (int i = 0; i < 4; ++i)
#pragma unroll
        for (int rg = 0; rg < 4; ++rg) {
            int row = mt * 64 + i * 16 + quad * 4 + rg;
            gm[i * 4 + rg] = gamma[row] * INV_;
            bt[i * 4 + rg] = beta[row];
        }

    if (MODE == 1) {
#pragma unroll
        for (int j = 0; j < 4; ++j) {
            int n = nt * 64 + j * 16 + ln;
            int bb = n >> 8;
            int cc = n & (C_ - 1);
            const ushort* gr = residT + (size_t)n * P_;       // gT row (b,c), indexed by o
            ushort* op = (ushort*)out + (size_t)bb * P_ * C_ + cc;
#pragma unroll
            for (int i = 0; i < 4; ++i) {
                int rbase = mt * 64 + i * 16 + quad * 4;
                ushort4 rv = *(const ushort4*)&gr[rbase];
                float rf[4] = {bf2f(rv.x), bf2f(rv.y), bf2f(rv.z), bf2f(rv.w)};
#pragma unroll
                for (int rg = 0; rg < 4; ++rg) {
                    int row = rbase + rg;
                    float v = fmaxf(acc[i][j][rg] * gm[i * 4 + rg] + bt[i * 4 + rg], 0.f) + rf[rg];
                    op[(size_t)row * C_] = f2bf(v);
                }
            }
        }
    } else {
#pragma unroll
        for (int j = 0; j < 4; ++j) {
            int n = nt * 64 + j * 16 + ln;
            int bb = n >> 11;
            int pp = n & (P_ - 1);
            float* op = (float*)out + (size_t)bb * C_ * P_ + pp;
#pragma unroll
            for (int i = 0; i < 4; ++i)
#pragma unroll
                for (int rg = 0; rg < 4; ++rg) {
                    int row = mt * 64 + i * 16 + quad * 4 + rg;
                    op[(size_t)row * P_] =
                        fmaxf(acc[i][j][rg] * gm[i * 4 + rg] + bt[i * 4 + rg], 0.f);
                }
        }
    }
}

// out[b][d][hw] = pos ? r[b][d][pos-1] : x[b][d][hw]
__global__ __launch_bounds__(256) void output_kernel(const float* __restrict__ x,
                                                     const int* __restrict__ pos,
                                                     const float* __restrict__ r,
                                                     float* __restrict__ out) {
    size_t v = (size_t)blockIdx.x * 256 + threadIdx.x;
    size_t e0 = v * 4;
    int hw = (int)(e0 & (HW_ - 1));
    int bc = (int)(e0 >> 14);
    int d = bc & (C_ - 1);
    int b = bc >> 8;
    float4 xv = *(const float4*)&x[e0];
    int4 pv = *(const int4*)&pos[b * HW_ + hw];
    const float* rrow = r + ((size_t)b * C_ + d) * P_;
    float4 ov = xv;
    if (pv.x) ov.x = rrow[pv.x - 1];
    if (pv.y) ov.y = rrow[pv.y - 1];
    if (pv.z) ov.z = rrow[pv.z - 1];
    if (pv.w) ov.w = rrow[pv.w - 1];
    *(float4*)&out[e0] = ov;
}

extern "C" void kernel_launch(void* const* d_in, const int* in_sizes, int n_in,
                              void* d_out, int out_size, void* d_ws, size_t ws_size,
                              hipStream_t stream) {
    const float* x    = (const float*)d_in[0];
    const float* edge = (const float*)d_in[1];
    const float* Wadj = (const float*)d_in[2];
    const float* ga   = (const float*)d_in[3];
    const float* be   = (const float*)d_in[4];
    const float* Wg   = (const float*)d_in[5];
    const float* gw   = (const float*)d_in[6];
    const float* bw   = (const float*)d_in[7];
    float* out = (float*)d_out;

    char* ws = (char*)d_ws;
    int*                ncand = (int*)(ws + OFF_NCAND);
    unsigned long long* cand  = (unsigned long long*)(ws + OFF_CAND);
    int*                topk  = (int*)(ws + OFF_TOPK);
    int*                pos   = (int*)(ws + OFF_POS);
    int*                rankb = (int*)(ws + OFF_RANK);
    ushort*             gT    = (ushort*)(ws + OFF_GT);
    ushort*             z2    = (ushort*)(ws + OFF_Z2);
    ushort*             WadjB = (ushort*)(ws + OFF_WADJB);
    ushort*             WgB   = (ushort*)(ws + OFF_WGB);
    float*              rbuf  = (float*)(ws + OFF_R);

    // ===== MEASUREMENT PROBE (R7): run the idempotent pipeline TWICE. =====
    // D = F + 2M where F = fixed per-invocation overhead inside dur_us and
    // M = marginal cost of one pipeline pass (kernels + launch gaps).
    // R6 measured F + M = 221.5us. This round decomposes it. Results are
    // byte-identical (second pass recomputes everything; output written last).
    for (int rep = 0; rep < 2; ++rep) {
        prep_kernel<<<PREP_GRID, 256, 0, stream>>>(Wadj, WadjB, Wg, WgB, pos, rankb, ncand);
        compact_kernel<<<B_ * 64, 256, 0, stream>>>(edge, cand, ncand);
        {
            dim3 grid(64, 64, B_);
            rank_partial_kernel<<<grid, 256, 0, stream>>>(cand, ncand, rankb);
        }
        {
            dim3 grid(64, B_);
            rank_finalize_kernel<<<grid, 256, 0, stream>>>(cand, ncand, rankb, topk, pos, edge);
        }
        gather_lds_kernel<<<B_ * C_, 256, 0, stream>>>(x, topk, gT);

        // GEMM1: M=2048, N=1024 (b,c), K=2048 -> 16 mt-pairs x 16 nt = 256 blocks x 2 waves
        gemm_wave_kernel<1, 2048, 16, 2><<<256, 128, 0, stream>>>(WadjB, gT, ga, be, gT, z2);
        // GEMM2: M=256, N=8192 (b,p), K=256 -> 4x128 wave tiles = 512 waves
        gemm_wave_kernel<2, 256, 128, 1><<<512, 64, 0, stream>>>(WgB, z2, gw, bw, nullptr, rbuf);

        output_kernel<<<(B_ * C_ * HW_) / 4 / 256, 256, 0, stream>>>(x, pos, rbuf, out);
    }
}

// Round 8
// 221.488 us; speedup vs baseline: 1.4882x; 1.4882x over previous
//
#include <hip/hip_runtime.h>
#include <stdint.h>

#define B_   4
#define C_   256
#define HW_  16384
#define P_   2048
#define THR_ 0.8f
#define INV_ 0.9999950000374997f

// ncand padded: counter b lives at ncand[b*16] (64 B apart -> no cacheline sharing)
#define NCIDX(b) ((b) << 4)

// ---------------- workspace layout (bytes) ----------------
#define OFF_NCAND 0
#define OFF_CAND  256                       // u64 cand[4][HW_]   512 KB
#define OFF_TOPK  524544                    // int topk[4][P_]     32 KB
#define OFF_POS   557312                    // int pos[4][HW_]    256 KB
#define OFF_G     819456                    // f32 r[4][C_][P_]     8 MB (GEMM2 out)
#define OFF_GT    9208064                   // bf16 gT[4][C_][P_]   4 MB  == [1024][2048]
#define OFF_Z2    13402368                  // bf16 z2[4][P_][C_]   4 MB  == [8192][256]
#define OFF_WADJB 17596672                  // bf16 Wadj[2048][2048] 8 MB
#define OFF_WGB   25985280                  // bf16 Wg[256][256]  128 KB
#define OFF_R     OFF_G
#define OFF_RANK  OFF_Z2                    // int rank[4][HW_] 256 KB, aliases z2 (dead before gemm1)

typedef __attribute__((ext_vector_type(8))) short bf16x8;
typedef __attribute__((ext_vector_type(4))) float f32x4;

__device__ __forceinline__ ushort f2bf(float f) {
    union { float f; unsigned u; } a; a.f = f;
    unsigned r = (a.u + 0x7fffu + ((a.u >> 16) & 1u)) >> 16;   // RNE
    return (ushort)r;
}
__device__ __forceinline__ float bf2f(ushort u) {
    union { unsigned u; float f; } a; a.u = (unsigned)u << 16;
    return a.f;
}

// Fused prep: convert Wadj (4096 blocks) + convert Wg (64 blocks) + zero pos/rank/ncand (128 blocks)
#define PREP_WADJ_BLOCKS 4096               // P_*P_/4/256
#define PREP_WG_BLOCKS   64                 // C_*C_/4/256
#define PREP_ZERO_BLOCKS 128                // (B_*HW_/4)*2 / 256
#define PREP_GRID (PREP_WADJ_BLOCKS + PREP_WG_BLOCKS + PREP_ZERO_BLOCKS)

__global__ __launch_bounds__(256) void prep_kernel(const float* __restrict__ Wadj,
                                                   ushort* __restrict__ WadjB,
                                                   const float* __restrict__ Wg,
                                                   ushort* __restrict__ WgB,
                                                   int* __restrict__ pos,
                                                   int* __restrict__ rankbuf,
                                                   int* __restrict__ ncand) {
    int bid = blockIdx.x;
    if (bid < PREP_WADJ_BLOCKS) {
        int i = bid * 256 + threadIdx.x;
        float4 v = ((const float4*)Wadj)[i];
        ushort4 o; o.x = f2bf(v.x); o.y = f2bf(v.y); o.z = f2bf(v.z); o.w = f2bf(v.w);
        ((ushort4*)WadjB)[i] = o;
    } else if (bid < PREP_WADJ_BLOCKS + PREP_WG_BLOCKS) {
        int i = (bid - PREP_WADJ_BLOCKS) * 256 + threadIdx.x;
        float4 v = ((const float4*)Wg)[i];
        ushort4 o; o.x = f2bf(v.x); o.y = f2bf(v.y); o.z = f2bf(v.z); o.w = f2bf(v.w);
        ((ushort4*)WgB)[i] = o;
    } else {
        int zb = bid - PREP_WADJ_BLOCKS - PREP_WG_BLOCKS;
        int i = zb * 256 + threadIdx.x;                // 0 .. 32767 (int4 units)
        int4 z = {0, 0, 0, 0};
        if (i < B_ * HW_ / 4) ((int4*)pos)[i] = z;
        else                  ((int4*)rankbuf)[i - B_ * HW_ / 4] = z;
        if (zb == 0 && threadIdx.x < 64) ncand[threadIdx.x] = 0;   // covers all padded slots
    }
}

// Block-aggregated compact: ballot+popcount per wave, LDS prefix across 4 waves,
// ONE global atomicAdd per block (256 total, padded counters). R6: -11.5us vs
// per-lane atomics on one shared cacheline.
__global__ __launch_bounds__(256) void compact_kernel(const float* __restrict__ edge,
                                                      unsigned long long* __restrict__ cand,
                                                      int* __restrict__ ncand) {
    int b = blockIdx.x >> 6;
    int i = (blockIdx.x & 63) * 256 + threadIdx.x;
    float e = edge[b * HW_ + i];
    bool act = (e >= THR_);
    unsigned long long mask = __ballot(act);
    int lane = threadIdx.x & 63;
    int wid  = threadIdx.x >> 6;
    int before = __popcll(mask & ((1ull << lane) - 1ull));
    __shared__ int wcnt[4];
    __shared__ int base;
    if (lane == 0) wcnt[wid] = __popcll(mask);
    __syncthreads();
    if (threadIdx.x == 0) {
        int c0 = wcnt[0], c1 = wcnt[1], c2 = wcnt[2], c3 = wcnt[3];
        wcnt[0] = 0; wcnt[1] = c0; wcnt[2] = c0 + c1; wcnt[3] = c0 + c1 + c2;
        base = atomicAdd(&ncand[NCIDX(b)], c0 + c1 + c2 + c3);
    }
    __syncthreads();
    if (act) {
        int slot = base + wcnt[wid] + before;
        unsigned vb = __float_as_uint(e);
        cand[(size_t)b * HW_ + slot] =
            ((unsigned long long)vb << 32) | (unsigned long long)(0xFFFFFFFFu - (unsigned)i);
    }
}

// 2-D partial rank: block (jb, tb, b) counts, for each candidate j in jb-tile,
// how many candidates in tb-tile compare greater. atomicAdd into rankbuf[j].
// NOTE R4 lesson: 2x2 super-tiling regressed — empty-block dispatch is nearly
// free; work concentration isn't.
__global__ __launch_bounds__(256) void rank_partial_kernel(
        const unsigned long long* __restrict__ cand,
        const int* __restrict__ ncand,
        int* __restrict__ rankbuf) {
    int b = blockIdx.z;
    int n = ncand[NCIDX(b)];
    int jb = blockIdx.x * 256, tb = blockIdx.y * 256;
    if (jb >= n || tb >= n) return;
    const unsigned long long* cb = cand + (size_t)b * HW_;
    __shared__ unsigned long long tile[256];
    int j = jb + threadIdx.x;
    unsigned long long kj = (j < n) ? cb[j] : 0ull;
    tile[threadIdx.x] = (tb + (int)threadIdx.x < n) ? cb[tb + threadIdx.x] : 0ull;
    __syncthreads();
    int cnt = 0;
#pragma unroll 16
    for (int k = 0; k < 256; ++k) cnt += (tile[k] > kj) ? 1 : 0;   // padded zeros never count
    if (j < n && cnt) atomicAdd(&rankbuf[b * HW_ + j], cnt);
}

// rank < P -> topk[rank]=idx, pos[idx]=rank+1.  Fallback (n < P) folded in.
__global__ __launch_bounds__(256) void rank_finalize_kernel(
        const unsigned long long* __restrict__ cand,
        const int* __restrict__ ncand,
        const int* __restrict__ rankbuf,
        int* __restrict__ topk,
        int* __restrict__ pos,
        const float* __restrict__ edge) {
    int b = blockIdx.y;
    int n = ncand[NCIDX(b)];
    int j = blockIdx.x * 256 + threadIdx.x;
    if (j < n) {
        int rank = rankbuf[b * HW_ + j];
        if (rank < P_) {
            int idx = (int)(0xFFFFFFFFu - (unsigned)(cand[(size_t)b * HW_ + j] & 0xFFFFFFFFull));
            topk[b * P_ + rank] = idx;
            pos[b * HW_ + idx] = rank + 1;
        }
    }
    if (n < P_ && blockIdx.x == 0 && threadIdx.x == 0) {
        int cnt = n;
        for (int i = 0; i < HW_ && cnt < P_; ++i) {
            if (edge[b * HW_ + i] < THR_) {
                topk[b * P_ + cnt] = i;
                pos[b * HW_ + i] = cnt + 1;
                cnt++;
            }
        }
    }
}

// index-driven gather: one block per (b,c) row; stage x-row in LDS (coalesced),
// gather topk positions from LDS, write gT row fully coalesced (16B/thread runs).
__global__ __launch_bounds__(256) void gather_lds_kernel(const float* __restrict__ x,
                                                         const int* __restrict__ topk,
                                                         ushort* __restrict__ gT) {
    __shared__ float row[HW_];              // 64 KB -> 2 blocks/CU
    int bc = blockIdx.x;                    // b*C_ + c
    int b = bc >> 8;
    const float* xr = x + (size_t)bc * HW_;
#pragma unroll
    for (int i = 0; i < 16; ++i)
        ((float4*)row)[threadIdx.x + i * 256] = ((const float4*)xr)[threadIdx.x + i * 256];
    __syncthreads();
    const int* tk = topk + b * P_;
    int p0 = threadIdx.x * 8;
    int4 i0 = *(const int4*)&tk[p0];
    int4 i1 = *(const int4*)&tk[p0 + 4];
    ushort4 o0, o1;
    o0.x = f2bf(row[i0.x]); o0.y = f2bf(row[i0.y]); o0.z = f2bf(row[i0.z]); o0.w = f2bf(row[i0.w]);
    o1.x = f2bf(row[i1.x]); o1.y = f2bf(row[i1.y]); o1.z = f2bf(row[i1.z]); o1.w = f2bf(row[i1.w]);
    ushort* gp = gT + (size_t)bc * P_ + p0;
    *(ushort4*)gp = o0;
    *(ushort4*)(gp + 4) = o1;
}

// ------------------- per-wave NT MFMA GEMM, no LDS, no barriers -------------------
// R7 probe attributed ~30-38us to gemm1 (0.5 waves/SIMD, 2-deep prefetch exposes
// L2/L3 load latency every 32-k chunk). R8: prefetch ring deepened to 4 K-chunks
// (128 staging VGPRs; ~210 total, no spill at our occupancy).
#define MFMA16(AB, BB)                                                              \
    _Pragma("unroll")                                                               \
    for (int i = 0; i < 4; ++i)                                                     \
    _Pragma("unroll")                                                               \
        for (int j = 0; j < 4; ++j)                                                 \
            acc[i][j] = __builtin_amdgcn_mfma_f32_16x16x32_bf16(                    \
                __builtin_bit_cast(bf16x8, AB[i]),                                  \
                __builtin_bit_cast(bf16x8, BB[j]), acc[i][j], 0, 0, 0);

// MODE 1 (gemm1): M=2048 (o), N=1024 (b*256+c), K=2048
// MODE 2 (gemm2): M=256 (d), N=8192 (b*2048+p), K=256
template<int MODE, int KDIM, int NTN, int WPB>
__global__ __launch_bounds__(64 * WPB) void gemm_wave_kernel(
        const ushort* __restrict__ A, const ushort* __restrict__ B,
        const float* __restrict__ gamma, const float* __restrict__ beta,
        const ushort* __restrict__ residT, void* __restrict__ out) {
    constexpr int KSTEPS = KDIM / 32;        // 32-k chunks; KSTEPS is a multiple of 4
    const int bid = blockIdx.x;
    const int wid = threadIdx.x >> 6;        // wave within block (0..WPB-1)
    const int mt = (bid / NTN) * WPB + wid;
    const int nt = bid % NTN;
    const int lane = threadIdx.x & 63;       // 0..63
    const int quad = lane >> 4, ln = lane & 15;

    const ushort* pa[4];
    const ushort* pb[4];
#pragma unroll
    for (int i = 0; i < 4; ++i) {
        pa[i] = A + (size_t)(mt * 64 + i * 16 + ln) * KDIM + quad * 8;
        pb[i] = B + (size_t)(nt * 64 + i * 16 + ln) * KDIM + quad * 8;
    }

    f32x4 acc[4][4];
#pragma unroll
    for (int i = 0; i < 4; ++i)
#pragma unroll
        for (int j = 0; j < 4; ++j) acc[i][j] = (f32x4){0.f, 0.f, 0.f, 0.f};

    // 4-deep prefetch ring: sets t=0..3 hold K-chunks s, s+1, s+2, s+3.
    uint4 A4[4][4], B4[4][4];
#pragma unroll
    for (int t = 0; t < 4; ++t)
#pragma unroll
        for (int i = 0; i < 4; ++i) {
            A4[t][i] = *(const uint4*)(pa[i] + t * 32);
            B4[t][i] = *(const uint4*)(pb[i] + t * 32);
        }

    int koff = 4 * 32;
    for (int s = 0; s < KSTEPS - 4; s += 4) {
#pragma unroll
        for (int t = 0; t < 4; ++t) {
            MFMA16(A4[t], B4[t])
#pragma unroll
            for (int i = 0; i < 4; ++i) {
                A4[t][i] = *(const uint4*)(pa[i] + koff + t * 32);
                B4[t][i] = *(const uint4*)(pb[i] + koff + t * 32);
            }
        }
        koff += 128;
    }
#pragma unroll
    for (int t = 0; t < 4; ++t) {
        MFMA16(A4[t], B4[t])
    }

    float gm[16], bt[16];
#pragma unroll
    for (int i = 0; i < 4; ++i)
#pragma unroll
        for (int rg = 0; rg < 4; ++rg) {
            int row = mt * 64 + i * 16 + quad * 4 + rg;
            gm[i * 4 + rg] = gamma[row] * INV_;
            bt[i * 4 + rg] = beta[row];
        }

    if (MODE == 1) {
#pragma unroll
        for (int j = 0; j < 4; ++j) {
            int n = nt * 64 + j * 16 + ln;
            int bb = n >> 8;
            int cc = n & (C_ - 1);
            const ushort* gr = residT + (size_t)n * P_;       // gT row (b,c), indexed by o
            ushort* op = (ushort*)out + (size_t)bb * P_ * C_ + cc;
#pragma unroll
            for (int i = 0; i < 4; ++i) {
                int rbase = mt * 64 + i * 16 + quad * 4;
                ushort4 rv = *(const ushort4*)&gr[rbase];
                float rf[4] = {bf2f(rv.x), bf2f(rv.y), bf2f(rv.z), bf2f(rv.w)};
#pragma unroll
                for (int rg = 0; rg < 4; ++rg) {
                    int row = rbase + rg;
                    float v = fmaxf(acc[i][j][rg] * gm[i * 4 + rg] + bt[i * 4 + rg], 0.f) + rf[rg];
                    op[(size_t)row * C_] = f2bf(v);
                }
            }
        }
    } else {
#pragma unroll
        for (int j = 0; j < 4; ++j) {
            int n = nt * 64 + j * 16 + ln;
            int bb = n >> 11;
            int pp = n & (P_ - 1);
            float* op = (float*)out + (size_t)bb * C_ * P_ + pp;
#pragma unroll
            for (int i = 0; i < 4; ++i)
#pragma unroll
                for (int rg = 0; rg < 4; ++rg) {
                    int row = mt * 64 + i * 16 + quad * 4 + rg;
                    op[(size_t)row * P_] =
                        fmaxf(acc[i][j][rg] * gm[i * 4 + rg] + bt[i * 4 + rg], 0.f);
                }
        }
    }
}

// out[b][d][hw] = pos ? r[b][d][pos-1] : x[b][d][hw]
__global__ __launch_bounds__(256) void output_kernel(const float* __restrict__ x,
                                                     const int* __restrict__ pos,
                                                     const float* __restrict__ r,
                                                     float* __restrict__ out) {
    size_t v = (size_t)blockIdx.x * 256 + threadIdx.x;
    size_t e0 = v * 4;
    int hw = (int)(e0 & (HW_ - 1));
    int bc = (int)(e0 >> 14);
    int d = bc & (C_ - 1);
    int b = bc >> 8;
    float4 xv = *(const float4*)&x[e0];
    int4 pv = *(const int4*)&pos[b * HW_ + hw];
    const float* rrow = r + ((size_t)b * C_ + d) * P_;
    float4 ov = xv;
    if (pv.x) ov.x = rrow[pv.x - 1];
    if (pv.y) ov.y = rrow[pv.y - 1];
    if (pv.z) ov.z = rrow[pv.z - 1];
    if (pv.w) ov.w = rrow[pv.w - 1];
    *(float4*)&out[e0] = ov;
}

extern "C" void kernel_launch(void* const* d_in, const int* in_sizes, int n_in,
                              void* d_out, int out_size, void* d_ws, size_t ws_size,
                              hipStream_t stream) {
    const float* x    = (const float*)d_in[0];
    const float* edge = (const float*)d_in[1];
    const float* Wadj = (const float*)d_in[2];
    const float* ga   = (const float*)d_in[3];
    const float* be   = (const float*)d_in[4];
    const float* Wg   = (const float*)d_in[5];
    const float* gw   = (const float*)d_in[6];
    const float* bw   = (const float*)d_in[7];
    float* out = (float*)d_out;

    char* ws = (char*)d_ws;
    int*                ncand = (int*)(ws + OFF_NCAND);
    unsigned long long* cand  = (unsigned long long*)(ws + OFF_CAND);
    int*                topk  = (int*)(ws + OFF_TOPK);
    int*                pos   = (int*)(ws + OFF_POS);
    int*                rankb = (int*)(ws + OFF_RANK);
    ushort*             gT    = (ushort*)(ws + OFF_GT);
    ushort*             z2    = (ushort*)(ws + OFF_Z2);
    ushort*             WadjB = (ushort*)(ws + OFF_WADJB);
    ushort*             WgB   = (ushort*)(ws + OFF_WGB);
    float*              rbuf  = (float*)(ws + OFF_R);

    prep_kernel<<<PREP_GRID, 256, 0, stream>>>(Wadj, WadjB, Wg, WgB, pos, rankb, ncand);
    compact_kernel<<<B_ * 64, 256, 0, stream>>>(edge, cand, ncand);
    {
        dim3 grid(64, 64, B_);
        rank_partial_kernel<<<grid, 256, 0, stream>>>(cand, ncand, rankb);
    }
    {
        dim3 grid(64, B_);
        rank_finalize_kernel<<<grid, 256, 0, stream>>>(cand, ncand, rankb, topk, pos, edge);
    }
    gather_lds_kernel<<<B_ * C_, 256, 0, stream>>>(x, topk, gT);

    // GEMM1: M=2048, N=1024 (b,c), K=2048 -> 16 mt-pairs x 16 nt = 256 blocks x 2 waves
    gemm_wave_kernel<1, 2048, 16, 2><<<256, 128, 0, stream>>>(WadjB, gT, ga, be, gT, z2);
    // GEMM2: M=256, N=8192 (b,p), K=256 -> 4x128 wave tiles = 512 waves
    gemm_wave_kernel<2, 256, 128, 1><<<512, 64, 0, stream>>>(WgB, z2, gw, bw, nullptr, rbuf);

    output_kernel<<<(B_ * C_ * HW_) / 4 / 256, 256, 0, stream>>>(x, pos, rbuf, out);
}